// Round 1
// baseline (485.401 us; speedup 1.0000x reference)
//
#include <hip/hip_runtime.h>

#define BIG 3.0e38f

// ---------------------------------------------------------------------------
// KNN (k=3) with inverse-distance weights.
// xyzF: [B, N, 3] fine query points, xyzC: [B, S, 3] coarse candidates.
// Outputs SoA: idx[(b*3+k)*N + n], w[(b*3+k)*N + n].
// One thread per query point; coarse set staged in LDS as float4 (w=|b|^2).
// ---------------------------------------------------------------------------
template <int S>
__global__ __launch_bounds__(256) void knn_kernel(const float* __restrict__ xyzF,
                                                  const float* __restrict__ xyzC,
                                                  int N,
                                                  int* __restrict__ idx,
                                                  float* __restrict__ w) {
    __shared__ float4 sc[S];
    const int b = blockIdx.y;
    const int tid = threadIdx.x;

    for (int i = tid; i < S; i += 256) {
        const float x = xyzC[(b * S + i) * 3 + 0];
        const float y = xyzC[(b * S + i) * 3 + 1];
        const float z = xyzC[(b * S + i) * 3 + 2];
        sc[i] = make_float4(x, y, z, x * x + y * y + z * z);
    }
    __syncthreads();

    const int n = blockIdx.x * 256 + tid;
    const float ax = xyzF[(b * N + n) * 3 + 0];
    const float ay = xyzF[(b * N + n) * 3 + 1];
    const float az = xyzF[(b * N + n) * 3 + 2];
    const float an = ax * ax + ay * ay + az * az;

    float d0 = BIG, d1 = BIG, d2 = BIG;
    int i0 = 0, i1 = 0, i2 = 0;

#pragma unroll 4
    for (int s = 0; s < S; ++s) {
        const float4 p = sc[s];
        const float t = ax * p.x + ay * p.y + az * p.z;
        const float d = an + p.w - 2.0f * t;  // matches ref formula
        if (d < d2) {
            if (d < d1) {
                if (d < d0) {
                    d2 = d1; i2 = i1;
                    d1 = d0; i1 = i0;
                    d0 = d;  i0 = s;
                } else {
                    d2 = d1; i2 = i1;
                    d1 = d;  i1 = s;
                }
            } else {
                d2 = d; i2 = s;
            }
        }
    }

    const float r0 = 1.0f / (d0 + 1e-8f);
    const float r1 = 1.0f / (d1 + 1e-8f);
    const float r2 = 1.0f / (d2 + 1e-8f);
    const float rs = r0 + r1 + r2;

    idx[(b * 3 + 0) * N + n] = i0;
    idx[(b * 3 + 1) * N + n] = i1;
    idx[(b * 3 + 2) * N + n] = i2;
    w[(b * 3 + 0) * N + n] = r0 / rs;
    w[(b * 3 + 1) * N + n] = r1 / rs;
    w[(b * 3 + 2) * N + n] = r2 / rs;
}

// ---------------------------------------------------------------------------
// Stage-1 output: inter1[B, 768, 2048] channel-major.
// c < 256  -> copy of x1[B,256,2048]
// c >= 256 -> 3-NN interp of x2[B,512,512] rows
// ---------------------------------------------------------------------------
__global__ __launch_bounds__(256) void build_inter1(const float* __restrict__ x1,
                                                    const float* __restrict__ x2,
                                                    const int* __restrict__ idx,
                                                    const float* __restrict__ w,
                                                    float* __restrict__ inter) {
    const int c = blockIdx.y;   // 0..767
    const int b = blockIdx.z;   // 0..3
    const int n = blockIdx.x * 256 + threadIdx.x;  // 0..2047

    float v;
    if (c < 256) {
        v = x1[(b * 256 + c) * 2048 + n];
    } else {
        const float* row = x2 + (size_t)(b * 512 + (c - 256)) * 512;
        const int j0 = idx[(b * 3 + 0) * 2048 + n];
        const int j1 = idx[(b * 3 + 1) * 2048 + n];
        const int j2 = idx[(b * 3 + 2) * 2048 + n];
        v = w[(b * 3 + 0) * 2048 + n] * row[j0]
          + w[(b * 3 + 1) * 2048 + n] * row[j1]
          + w[(b * 3 + 2) * 2048 + n] * row[j2];
    }
    inter[((size_t)b * 768 + c) * 2048 + n] = v;
}

// ---------------------------------------------------------------------------
// Final output: out[B, 896, 8192].
// d < 128  -> copy of x0[B,128,8192]
// d >= 128 -> 3-NN interp of inter1[B,768,2048] rows
// ---------------------------------------------------------------------------
__global__ __launch_bounds__(256) void final_out(const float* __restrict__ x0,
                                                 const float* __restrict__ inter,
                                                 const int* __restrict__ idx,
                                                 const float* __restrict__ w,
                                                 float* __restrict__ out) {
    const int d = blockIdx.y;   // 0..895
    const int b = blockIdx.z;   // 0..3
    const int n = blockIdx.x * 256 + threadIdx.x;  // 0..8191

    float v;
    if (d < 128) {
        v = x0[((size_t)b * 128 + d) * 8192 + n];
    } else {
        const float* row = inter + ((size_t)b * 768 + (d - 128)) * 2048;
        const int j0 = idx[(b * 3 + 0) * 8192 + n];
        const int j1 = idx[(b * 3 + 1) * 8192 + n];
        const int j2 = idx[(b * 3 + 2) * 8192 + n];
        v = w[(b * 3 + 0) * 8192 + n] * row[j0]
          + w[(b * 3 + 1) * 8192 + n] * row[j1]
          + w[(b * 3 + 2) * 8192 + n] * row[j2];
    }
    out[((size_t)b * 896 + d) * 8192 + n] = v;
}

extern "C" void kernel_launch(void* const* d_in, const int* in_sizes, int n_in,
                              void* d_out, int out_size, void* d_ws, size_t ws_size,
                              hipStream_t stream) {
    const float* xyz0 = (const float*)d_in[0];  // [4,8192,3]
    const float* xyz1 = (const float*)d_in[1];  // [4,2048,3]
    const float* xyz2 = (const float*)d_in[2];  // [4,512,3]
    const float* x0   = (const float*)d_in[3];  // [4,128,8192]
    const float* x1   = (const float*)d_in[4];  // [4,256,2048]
    const float* x2   = (const float*)d_in[5];  // [4,512,512]
    float* out = (float*)d_out;                 // [4,896,8192]

    // Workspace layout (bytes, 16B-aligned):
    //   idx1  : int  [4*3*2048]       @ 0        (98304)
    //   w1    : float[4*3*2048]       @ 98304    (98304)
    //   inter1: float[4*768*2048]     @ 196608   (25165824)
    //   idx2  : int  [4*3*8192]       @ 25362432 (393216)
    //   w2    : float[4*3*8192]       @ 25755648 (393216)
    char* ws = (char*)d_ws;
    int*   idx1  = (int*)(ws + 0);
    float* w1    = (float*)(ws + 98304);
    float* inter = (float*)(ws + 196608);
    int*   idx2  = (int*)(ws + 25362432);
    float* w2    = (float*)(ws + 25755648);

    // Stage 1: fine=xyz1 (N=2048), coarse=xyz2 (S=512)
    knn_kernel<512><<<dim3(2048 / 256, 4), 256, 0, stream>>>(xyz1, xyz2, 2048, idx1, w1);
    build_inter1<<<dim3(2048 / 256, 768, 4), 256, 0, stream>>>(x1, x2, idx1, w1, inter);

    // Stage 2: fine=xyz0 (N=8192), coarse=xyz1 (S=2048)
    knn_kernel<2048><<<dim3(8192 / 256, 4), 256, 0, stream>>>(xyz0, xyz1, 8192, idx2, w2);
    final_out<<<dim3(8192 / 256, 896, 4), 256, 0, stream>>>(x0, inter, idx2, w2, out);
}

// Round 3
// 338.499 us; speedup vs baseline: 1.4340x; 1.4340x over previous
//
#include <hip/hip_runtime.h>

#define BIG 3.0e38f

// ---------------------------------------------------------------------------
// Partial KNN (k=3) over one chunk of the candidate set.
// xyzF: [B,N,3] queries, xyzC: [B,S,3] candidates.
// Block handles 256 queries x CHUNK candidates (chunk ch = blockIdx.y).
// Writes partial top-3 (dist, global index) SoA:
//   pd[((b*nC + ch)*3 + k)*N + n], pi[same]
// ---------------------------------------------------------------------------
template <int CHUNK>
__global__ __launch_bounds__(256) void knn_partial(const float* __restrict__ xyzF,
                                                   const float* __restrict__ xyzC,
                                                   int N,
                                                   float* __restrict__ pd,
                                                   int* __restrict__ pi) {
    __shared__ float4 sc[CHUNK];
    const int b = blockIdx.z;
    const int ch = blockIdx.y;
    const int nC = gridDim.y;
    const int tid = threadIdx.x;
    const int S = nC * CHUNK;
    const int base = ch * CHUNK;

    for (int i = tid; i < CHUNK; i += 256) {
        const float x = xyzC[(b * S + base + i) * 3 + 0];
        const float y = xyzC[(b * S + base + i) * 3 + 1];
        const float z = xyzC[(b * S + base + i) * 3 + 2];
        sc[i] = make_float4(x, y, z, x * x + y * y + z * z);
    }
    __syncthreads();

    const int n = blockIdx.x * 256 + tid;
    const float ax = xyzF[(b * N + n) * 3 + 0];
    const float ay = xyzF[(b * N + n) * 3 + 1];
    const float az = xyzF[(b * N + n) * 3 + 2];
    const float an = ax * ax + ay * ay + az * az;

    float d0 = BIG, d1 = BIG, d2 = BIG;
    int i0 = 0, i1 = 0, i2 = 0;

#pragma unroll 4
    for (int s = 0; s < CHUNK; ++s) {
        const float4 p = sc[s];
        const float t = ax * p.x + ay * p.y + az * p.z;
        const float d = an + p.w - 2.0f * t;  // matches ref formula exactly
        if (d < d2) {
            if (d < d1) {
                if (d < d0) {
                    d2 = d1; i2 = i1;
                    d1 = d0; i1 = i0;
                    d0 = d;  i0 = base + s;
                } else {
                    d2 = d1; i2 = i1;
                    d1 = d;  i1 = base + s;
                }
            } else {
                d2 = d; i2 = base + s;
            }
        }
    }

    const size_t o = ((size_t)(b * nC + ch) * 3) * N + n;
    pd[o + 0 * N] = d0;  pi[o + 0 * N] = i0;
    pd[o + 1 * N] = d1;  pi[o + 1 * N] = i1;
    pd[o + 2 * N] = d2;  pi[o + 2 * N] = i2;
}

// ---------------------------------------------------------------------------
// Merge nC partial top-3 lists -> final top-3 + inverse-distance weights.
// Insert in (chunk, k) order with strict < : preserves earliest-index ties,
// matching a sequential scan / jax.lax.top_k tie behavior.
// ---------------------------------------------------------------------------
__global__ __launch_bounds__(256) void knn_merge(const float* __restrict__ pd,
                                                 const int* __restrict__ pi,
                                                 int N, int nC,
                                                 int* __restrict__ idx,
                                                 float* __restrict__ w) {
    const int b = blockIdx.y;
    const int n = blockIdx.x * 256 + threadIdx.x;

    float d0 = BIG, d1 = BIG, d2 = BIG;
    int i0 = 0, i1 = 0, i2 = 0;

    for (int ch = 0; ch < nC; ++ch) {
        const size_t o = ((size_t)(b * nC + ch) * 3) * N + n;
#pragma unroll
        for (int k = 0; k < 3; ++k) {
            const float d = pd[o + (size_t)k * N];
            const int ii = pi[o + (size_t)k * N];
            if (d < d2) {
                if (d < d1) {
                    if (d < d0) {
                        d2 = d1; i2 = i1;
                        d1 = d0; i1 = i0;
                        d0 = d;  i0 = ii;
                    } else {
                        d2 = d1; i2 = i1;
                        d1 = d;  i1 = ii;
                    }
                } else {
                    d2 = d; i2 = ii;
                }
            }
        }
    }

    const float r0 = 1.0f / (d0 + 1e-8f);
    const float r1 = 1.0f / (d1 + 1e-8f);
    const float r2 = 1.0f / (d2 + 1e-8f);
    const float rs = r0 + r1 + r2;

    idx[(b * 3 + 0) * N + n] = i0;
    idx[(b * 3 + 1) * N + n] = i1;
    idx[(b * 3 + 2) * N + n] = i2;
    w[(b * 3 + 0) * N + n] = r0 / rs;
    w[(b * 3 + 1) * N + n] = r1 / rs;
    w[(b * 3 + 2) * N + n] = r2 / rs;
}

// ---------------------------------------------------------------------------
// Stage-1 interp-only output: inter[B, 512, 2048]  (x2 channels at xyz1 pts).
// Block = (n-tile 256, c-chunk of 16, b); idx/w loaded once per thread.
// ---------------------------------------------------------------------------
#define CCH 16
__global__ __launch_bounds__(256) void build_inter(const float* __restrict__ x2,
                                                   const int* __restrict__ idx,
                                                   const float* __restrict__ w,
                                                   float* __restrict__ inter) {
    const int b = blockIdx.z;
    const int n = blockIdx.x * 256 + threadIdx.x;  // 0..2047

    const int j0 = idx[(b * 3 + 0) * 2048 + n];
    const int j1 = idx[(b * 3 + 1) * 2048 + n];
    const int j2 = idx[(b * 3 + 2) * 2048 + n];
    const float w0 = w[(b * 3 + 0) * 2048 + n];
    const float w1 = w[(b * 3 + 1) * 2048 + n];
    const float w2 = w[(b * 3 + 2) * 2048 + n];

#pragma unroll
    for (int cc = 0; cc < CCH; ++cc) {
        const int c = blockIdx.y * CCH + cc;  // 0..511
        const float* row = x2 + (size_t)(b * 512 + c) * 512;
        const float v = w0 * row[j0] + w1 * row[j1] + w2 * row[j2];
        inter[((size_t)b * 512 + c) * 2048 + n] = v;
    }
}

// ---------------------------------------------------------------------------
// Final output: out[B, 896, 8192].
//   d < 128          -> copy of x0[B,128,8192]
//   128 <= d < 384   -> gather-interp from x1[B,256,2048] rows
//   d >= 384         -> gather-interp from inter[B,512,2048] rows
// Block = (n-tile 256, d-chunk of 32, b); idx/w loaded once per thread.
// ---------------------------------------------------------------------------
#define DCH 32
__global__ __launch_bounds__(256) void final_out(const float* __restrict__ x0,
                                                 const float* __restrict__ x1,
                                                 const float* __restrict__ inter,
                                                 const int* __restrict__ idx,
                                                 const float* __restrict__ w,
                                                 float* __restrict__ out) {
    const int b = blockIdx.z;
    const int n = blockIdx.x * 256 + threadIdx.x;  // 0..8191

    const int j0 = idx[(b * 3 + 0) * 8192 + n];
    const int j1 = idx[(b * 3 + 1) * 8192 + n];
    const int j2 = idx[(b * 3 + 2) * 8192 + n];
    const float w0 = w[(b * 3 + 0) * 8192 + n];
    const float w1 = w[(b * 3 + 1) * 8192 + n];
    const float w2 = w[(b * 3 + 2) * 8192 + n];

#pragma unroll
    for (int dd = 0; dd < DCH; ++dd) {
        const int d = blockIdx.y * DCH + dd;  // 0..895
        float v;
        if (d < 128) {
            v = x0[((size_t)b * 128 + d) * 8192 + n];
        } else {
            const int c = d - 128;
            const float* row = (c < 256)
                ? x1 + (size_t)(b * 256 + c) * 2048
                : inter + (size_t)(b * 512 + (c - 256)) * 2048;
            v = w0 * row[j0] + w1 * row[j1] + w2 * row[j2];
        }
        out[((size_t)b * 896 + d) * 8192 + n] = v;
    }
}

extern "C" void kernel_launch(void* const* d_in, const int* in_sizes, int n_in,
                              void* d_out, int out_size, void* d_ws, size_t ws_size,
                              hipStream_t stream) {
    const float* xyz0 = (const float*)d_in[0];  // [4,8192,3]
    const float* xyz1 = (const float*)d_in[1];  // [4,2048,3]
    const float* xyz2 = (const float*)d_in[2];  // [4,512,3]
    const float* x0   = (const float*)d_in[3];  // [4,128,8192]
    const float* x1   = (const float*)d_in[4];  // [4,256,2048]
    const float* x2   = (const float*)d_in[5];  // [4,512,512]
    float* out = (float*)d_out;                 // [4,896,8192]

    // Workspace layout (bytes):
    //   inter : float[4*512*2048]   @ 0          (16,777,216)
    //   idx1  : int  [4*3*2048]     @ 16,777,216 (98,304)
    //   w1    : float[4*3*2048]     @ 16,875,520 (98,304)
    //   idx2  : int  [4*3*8192]     @ 16,973,824 (393,216)
    //   w2    : float[4*3*8192]     @ 17,367,040 (393,216)
    //   pd    : float[4*8*3*8192]   @ 17,760,256 (3,145,728)  (shared by both stages)
    //   pi    : int  [4*8*3*8192]   @ 20,905,984 (3,145,728)
    char* ws = (char*)d_ws;
    float* inter = (float*)(ws + 0);
    int*   idx1  = (int*)(ws + 16777216);
    float* w1    = (float*)(ws + 16875520);
    int*   idx2  = (int*)(ws + 16973824);
    float* w2    = (float*)(ws + 17367040);
    float* pd    = (float*)(ws + 17760256);
    int*   pi    = (int*)(ws + 20905984);

    // Stage 1: queries=xyz1 (N=2048), candidates=xyz2 (S=512, 8 chunks of 64)
    knn_partial<64><<<dim3(2048 / 256, 8, 4), 256, 0, stream>>>(xyz1, xyz2, 2048, pd, pi);
    knn_merge<<<dim3(2048 / 256, 4), 256, 0, stream>>>(pd, pi, 2048, 8, idx1, w1);
    build_inter<<<dim3(2048 / 256, 512 / CCH, 4), 256, 0, stream>>>(x2, idx1, w1, inter);

    // Stage 2: queries=xyz0 (N=8192), candidates=xyz1 (S=2048, 8 chunks of 256)
    knn_partial<256><<<dim3(8192 / 256, 8, 4), 256, 0, stream>>>(xyz0, xyz1, 8192, pd, pi);
    knn_merge<<<dim3(8192 / 256, 4), 256, 0, stream>>>(pd, pi, 8192, 8, idx2, w2);
    final_out<<<dim3(8192 / 256, 896 / DCH, 4), 256, 0, stream>>>(x0, x1, inter, idx2, w2, out);
}

// Round 4
// 273.114 us; speedup vs baseline: 1.7773x; 1.2394x over previous
//
#include <hip/hip_runtime.h>

#define BIG 3.0e38f

// ---------------------------------------------------------------------------
// Partial KNN (k=3) over one chunk of the candidate set. (unchanged, known-good)
// ---------------------------------------------------------------------------
template <int CHUNK>
__global__ __launch_bounds__(256) void knn_partial(const float* __restrict__ xyzF,
                                                   const float* __restrict__ xyzC,
                                                   int N,
                                                   float* __restrict__ pd,
                                                   int* __restrict__ pi) {
    __shared__ float4 sc[CHUNK];
    const int b = blockIdx.z;
    const int ch = blockIdx.y;
    const int nC = gridDim.y;
    const int tid = threadIdx.x;
    const int S = nC * CHUNK;
    const int base = ch * CHUNK;

    for (int i = tid; i < CHUNK; i += 256) {
        const float x = xyzC[(b * S + base + i) * 3 + 0];
        const float y = xyzC[(b * S + base + i) * 3 + 1];
        const float z = xyzC[(b * S + base + i) * 3 + 2];
        sc[i] = make_float4(x, y, z, x * x + y * y + z * z);
    }
    __syncthreads();

    const int n = blockIdx.x * 256 + tid;
    const float ax = xyzF[(b * N + n) * 3 + 0];
    const float ay = xyzF[(b * N + n) * 3 + 1];
    const float az = xyzF[(b * N + n) * 3 + 2];
    const float an = ax * ax + ay * ay + az * az;

    float d0 = BIG, d1 = BIG, d2 = BIG;
    int i0 = 0, i1 = 0, i2 = 0;

#pragma unroll 4
    for (int s = 0; s < CHUNK; ++s) {
        const float4 p = sc[s];
        const float t = ax * p.x + ay * p.y + az * p.z;
        const float d = an + p.w - 2.0f * t;  // matches ref formula exactly
        if (d < d2) {
            if (d < d1) {
                if (d < d0) {
                    d2 = d1; i2 = i1;
                    d1 = d0; i1 = i0;
                    d0 = d;  i0 = base + s;
                } else {
                    d2 = d1; i2 = i1;
                    d1 = d;  i1 = base + s;
                }
            } else {
                d2 = d; i2 = base + s;
            }
        }
    }

    const size_t o = ((size_t)(b * nC + ch) * 3) * N + n;
    pd[o + 0 * N] = d0;  pi[o + 0 * N] = i0;
    pd[o + 1 * N] = d1;  pi[o + 1 * N] = i1;
    pd[o + 2 * N] = d2;  pi[o + 2 * N] = i2;
}

// ---------------------------------------------------------------------------
// Merge nC partial top-3 lists -> final top-3 + inverse-distance weights.
// Block = 64 threads (more blocks in flight than R3's 256).
// ---------------------------------------------------------------------------
__global__ __launch_bounds__(64) void knn_merge(const float* __restrict__ pd,
                                                const int* __restrict__ pi,
                                                int N, int nC,
                                                int* __restrict__ idx,
                                                float* __restrict__ w) {
    const int b = blockIdx.y;
    const int n = blockIdx.x * 64 + threadIdx.x;

    float d0 = BIG, d1 = BIG, d2 = BIG;
    int i0 = 0, i1 = 0, i2 = 0;

    for (int ch = 0; ch < nC; ++ch) {
        const size_t o = ((size_t)(b * nC + ch) * 3) * N + n;
#pragma unroll
        for (int k = 0; k < 3; ++k) {
            const float d = pd[o + (size_t)k * N];
            const int ii = pi[o + (size_t)k * N];
            if (d < d2) {
                if (d < d1) {
                    if (d < d0) {
                        d2 = d1; i2 = i1;
                        d1 = d0; i1 = i0;
                        d0 = d;  i0 = ii;
                    } else {
                        d2 = d1; i2 = i1;
                        d1 = d;  i1 = ii;
                    }
                } else {
                    d2 = d; i2 = ii;
                }
            }
        }
    }

    const float r0 = 1.0f / (d0 + 1e-8f);
    const float r1 = 1.0f / (d1 + 1e-8f);
    const float r2 = 1.0f / (d2 + 1e-8f);
    const float rs = r0 + r1 + r2;

    idx[(b * 3 + 0) * N + n] = i0;
    idx[(b * 3 + 1) * N + n] = i1;
    idx[(b * 3 + 2) * N + n] = i2;
    w[(b * 3 + 0) * N + n] = r0 / rs;
    w[(b * 3 + 1) * N + n] = r1 / rs;
    w[(b * 3 + 2) * N + n] = r2 / rs;
}

// ---------------------------------------------------------------------------
// Generic channel-major [B,C,N] -> point-major out[b][n][co + c] (row stride OS).
// 64x64 LDS tile, +1 pad; both global read and write coalesced.
// ---------------------------------------------------------------------------
__global__ __launch_bounds__(256) void transpose_pm(const float* __restrict__ in,
                                                    float* __restrict__ out,
                                                    int C, int N, int OS, int co) {
    __shared__ float s[64][65];
    const int b = blockIdx.z;
    const int nb = blockIdx.x * 64;
    const int cb = blockIdx.y * 64;
    const int lo = threadIdx.x & 63;
    const int r  = threadIdx.x >> 6;

#pragma unroll
    for (int i = 0; i < 16; ++i) {
        const int cl = r + 4 * i;
        s[cl][lo] = in[((size_t)b * C + cb + cl) * N + nb + lo];
    }
    __syncthreads();
#pragma unroll
    for (int i = 0; i < 16; ++i) {
        const int pl = r + 4 * i;
        out[((size_t)b * N + nb + pl) * OS + co + cb + lo] = s[lo][pl];
    }
}

// ---------------------------------------------------------------------------
// Stage-1 interp, point-major: featP[b][n][256+c] = sum_k w_k * x2P[b][j_k][c].
// Wave handles one point's 64-channel segment -> all reads/writes coalesced.
// ---------------------------------------------------------------------------
__global__ __launch_bounds__(256) void interp1(const float* __restrict__ x2P,
                                               const int* __restrict__ idx,
                                               const float* __restrict__ w,
                                               float* __restrict__ featP) {
    __shared__ int   sj[3][64];
    __shared__ float sw[3][64];
    const int b = blockIdx.z;
    const int nb = blockIdx.x * 64;
    const int cb = blockIdx.y * 64;
    const int tid = threadIdx.x;

    if (tid < 64) {
#pragma unroll
        for (int k = 0; k < 3; ++k) {
            sj[k][tid] = idx[(b * 3 + k) * 2048 + nb + tid];
            sw[k][tid] = w[(b * 3 + k) * 2048 + nb + tid];
        }
    }
    __syncthreads();

    const int c = tid & 63, r = tid >> 6;
#pragma unroll
    for (int i = 0; i < 16; ++i) {
        const int p = r + 4 * i;
        const float v = sw[0][p] * x2P[((size_t)b * 512 + sj[0][p]) * 512 + cb + c]
                      + sw[1][p] * x2P[((size_t)b * 512 + sj[1][p]) * 512 + cb + c]
                      + sw[2][p] * x2P[((size_t)b * 512 + sj[2][p]) * 512 + cb + c];
        featP[((size_t)b * 2048 + nb + p) * 768 + 256 + cb + c] = v;
    }
}

// ---------------------------------------------------------------------------
// Final interp: out[b][128+c][n] = sum_k w_k * featP[b][j_k][c].
// 64pt x 64ch tile; coalesced featP row-segment reads; LDS tile transpose for
// coalesced channel-major writes. XCD swizzle: all 12 c-tiles of an n-tile on
// the same XCD (gather-row L2 reuse).
// ---------------------------------------------------------------------------
__global__ __launch_bounds__(256) void final_interp(const float* __restrict__ featP,
                                                    const int* __restrict__ idx,
                                                    const float* __restrict__ w,
                                                    float* __restrict__ out) {
    __shared__ float tile[64][65];
    __shared__ int   sj[3][64];
    __shared__ float sw[3][64];
    const int b = blockIdx.y;
    // 1536 blocks: xcd = id%8; q = id/8; ntile = xcd*16 + q%16 (128 total); ctile = q/16 (12)
    const int id = blockIdx.x;
    const int ntile = (id & 7) * 16 + ((id >> 3) & 15);
    const int ctile = id >> 7;
    const int nb = ntile * 64;
    const int cb = ctile * 64;
    const int tid = threadIdx.x;

    if (tid < 64) {
#pragma unroll
        for (int k = 0; k < 3; ++k) {
            sj[k][tid] = idx[(b * 3 + k) * 8192 + nb + tid];
            sw[k][tid] = w[(b * 3 + k) * 8192 + nb + tid];
        }
    }
    __syncthreads();

    {
        const int c = tid & 63, r = tid >> 6;
#pragma unroll
        for (int i = 0; i < 16; ++i) {
            const int p = r + 4 * i;
            const float v = sw[0][p] * featP[((size_t)b * 2048 + sj[0][p]) * 768 + cb + c]
                          + sw[1][p] * featP[((size_t)b * 2048 + sj[1][p]) * 768 + cb + c]
                          + sw[2][p] * featP[((size_t)b * 2048 + sj[2][p]) * 768 + cb + c];
            tile[p][c] = v;
        }
    }
    __syncthreads();
    {
        const int p = tid & 63, r = tid >> 6;
#pragma unroll
        for (int i = 0; i < 16; ++i) {
            const int cl = r + 4 * i;
            out[((size_t)b * 896 + 128 + cb + cl) * 8192 + nb + p] = tile[p][cl];
        }
    }
}

// ---------------------------------------------------------------------------
// out channels 0..127 = x0 (contiguous per batch), float4 copy.
// ---------------------------------------------------------------------------
__global__ __launch_bounds__(256) void copy_x0(const float4* __restrict__ x0,
                                               float4* __restrict__ out) {
    const int b = blockIdx.y;
    const int i = blockIdx.x * 256 + threadIdx.x;          // 0..262143 (128*8192/4)
    out[(size_t)b * (896 * 2048) + i] = x0[(size_t)b * (128 * 2048) + i];
}

extern "C" void kernel_launch(void* const* d_in, const int* in_sizes, int n_in,
                              void* d_out, int out_size, void* d_ws, size_t ws_size,
                              hipStream_t stream) {
    const float* xyz0 = (const float*)d_in[0];  // [4,8192,3]
    const float* xyz1 = (const float*)d_in[1];  // [4,2048,3]
    const float* xyz2 = (const float*)d_in[2];  // [4,512,3]
    const float* x0   = (const float*)d_in[3];  // [4,128,8192]
    const float* x1   = (const float*)d_in[4];  // [4,256,2048]
    const float* x2   = (const float*)d_in[5];  // [4,512,512]
    float* out = (float*)d_out;                 // [4,896,8192]

    // Workspace layout (bytes):
    //   featP : float[4*2048*768]  @ 0          (25,165,824)  point-major features at xyz1
    //   idx1  : int  [4*3*2048]    @ 25,165,824 (98,304)
    //   w1    : float[4*3*2048]    @ 25,264,128 (98,304)
    //   idx2  : int  [4*3*8192]    @ 25,362,432 (393,216)
    //   w2    : float[4*3*8192]    @ 25,755,648 (393,216)
    //   regionB @ 26,148,864: pd (3,145,728) + pi (3,145,728); x2P (4,194,304)
    //     aliases pd/pi — safe by ordering: knn1 -> merge1 -> t_x2 (clobbers pd/pi)
    //     -> interp1 (reads x2P) -> knn2 (clobbers x2P) -> merge2 -> final.
    char* ws = (char*)d_ws;
    float* featP = (float*)(ws + 0);
    int*   idx1  = (int*)(ws + 25165824);
    float* w1    = (float*)(ws + 25264128);
    int*   idx2  = (int*)(ws + 25362432);
    float* w2    = (float*)(ws + 25755648);
    float* pd    = (float*)(ws + 26148864);
    int*   pi    = (int*)(ws + 29294592);
    float* x2P   = (float*)(ws + 26148864);  // aliases pd/pi (see ordering above)

    // Stage-1 KNN: queries=xyz1 (N=2048), candidates=xyz2 (S=512, 8 chunks of 64)
    knn_partial<64><<<dim3(8, 8, 4), 256, 0, stream>>>(xyz1, xyz2, 2048, pd, pi);
    knn_merge<<<dim3(2048 / 64, 4), 64, 0, stream>>>(pd, pi, 2048, 8, idx1, w1);

    // Point-major staging (t_x2 clobbers pd/pi — they are dead after merge1)
    transpose_pm<<<dim3(512 / 64, 512 / 64, 4), 256, 0, stream>>>(x2, x2P, 512, 512, 512, 0);
    transpose_pm<<<dim3(2048 / 64, 256 / 64, 4), 256, 0, stream>>>(x1, featP, 256, 2048, 768, 0);
    interp1<<<dim3(2048 / 64, 512 / 64, 4), 256, 0, stream>>>(x2P, idx1, w1, featP);

    // Stage-2 KNN: queries=xyz0 (N=8192), candidates=xyz1 (S=2048, 8 chunks of 256)
    // (clobbers x2P — dead after interp1)
    knn_partial<256><<<dim3(32, 8, 4), 256, 0, stream>>>(xyz0, xyz1, 8192, pd, pi);
    knn_merge<<<dim3(8192 / 64, 4), 64, 0, stream>>>(pd, pi, 8192, 8, idx2, w2);

    // Output
    copy_x0<<<dim3(1024, 4), 256, 0, stream>>>((const float4*)x0, (float4*)out);
    final_interp<<<dim3(1536, 4), 256, 0, stream>>>(featP, idx2, w2, out);
}